// Round 12
// baseline (525.686 us; speedup 1.0000x reference)
//
#include <hip/hip_runtime.h>
#include <hip/hip_bf16.h>
#include <stdint.h>

// Problem constants: B=2, T=2048, D=1024, H=16, dh=64
#define Tq 2048
#define Dd 1024
#define Hh 16

typedef unsigned short u16;
typedef __attribute__((ext_vector_type(8))) short short8;
typedef __attribute__((ext_vector_type(4))) float f32x4;

__device__ __forceinline__ u16 f2bf(float f) {
  union { float f; unsigned u; } v; v.f = f;
  unsigned r = (v.u + 0x7fffu + ((v.u >> 16) & 1u)) >> 16;  // RNE
  return (u16)r;
}

__device__ __forceinline__ unsigned pk2bf(float a, float b) {
  __hip_bfloat162 h = __float22bfloat162_rn(float2{a, b});
  union { __hip_bfloat162 h; unsigned u; } c; c.h = h;
  return c.u;
}

__device__ __forceinline__ void load_lds16(const void* g, void* l) {
  __builtin_amdgcn_global_load_lds(
      (const __attribute__((address_space(1))) unsigned*)g,
      (__attribute__((address_space(3))) unsigned*)l, 16, 0, 0);
}

__device__ __forceinline__ f32x4 mfma16(short8 a, short8 b, f32x4 c) {
  return __builtin_amdgcn_mfma_f32_16x16x32_bf16(a, b, c, 0, 0, 0);
}

// Cross-lane word redistribution for the PV A-fragment. Builtins preferred:
// the compiler's hazard recognizer inserts the DPP-read wait states that a
// raw asm block does not get (round-2 failure: sporadic stale lanes).
__device__ __forceinline__ void permswap(unsigned& xx, unsigned& yy) {
#if __has_builtin(__builtin_amdgcn_permlane32_swap) && \
    __has_builtin(__builtin_amdgcn_permlane16_swap)
  typedef __attribute__((ext_vector_type(2))) unsigned uint2v;
  uint2v t0 = __builtin_amdgcn_permlane32_swap(xx, yy, false, false);
  uint2v t1 = __builtin_amdgcn_permlane16_swap(t0[0], t0[1], false, false);
  xx = t1[0];
  yy = t1[1];
#else
  asm volatile(
      "s_nop 1\n\t"
      "v_permlane32_swap_b32 %0, %1\n\t"
      "s_nop 1\n\t"
      "v_permlane16_swap_b32 %0, %1\n\t"
      "s_nop 1"
      : "+v"(xx), "+v"(yy));
#endif
}

// ------------------------------------------------------------- fused prep
// blocks [0,4096): LayerNorm rows
// blocks [4096,8192): 4x weight transpose (KxN fp32 -> NxK bf16)
// blocks [8192,9216): mask bit-pack (b,q,k)->bits[b][q/32][k]
// blocks [9216,9228): bias concat
__global__ __launch_bounds__(256) void prep_kernel(
    const float* __restrict__ x, const float* __restrict__ gamma,
    const float* __restrict__ beta, u16* __restrict__ xn,
    const float* __restrict__ W0, const float* __restrict__ W1,
    const float* __restrict__ W2, const float* __restrict__ W3,
    u16* __restrict__ o_qkv, u16* __restrict__ o_o,
    const int* __restrict__ mask, uint32_t* __restrict__ bits,
    const float* __restrict__ bq, const float* __restrict__ bk,
    const float* __restrict__ bv, float* __restrict__ bias3) {
  __shared__ float t[32][33];
  int idx = blockIdx.x;
  int tid = threadIdx.x;
  if (idx < 4096) {
    // ---- LayerNorm
    int row = idx;
    const float4 v = ((const float4*)(x + (size_t)row * Dd))[tid];
    float s = v.x + v.y + v.z + v.w;
    float s2 = v.x * v.x + v.y * v.y + v.z * v.z + v.w * v.w;
#pragma unroll
    for (int off = 1; off < 64; off <<= 1) {
      s += __shfl_xor(s, off);
      s2 += __shfl_xor(s2, off);
    }
    int w = tid >> 6;
    if ((tid & 63) == 0) { t[0][w] = s; t[0][4 + w] = s2; }
    __syncthreads();
    s = t[0][0] + t[0][1] + t[0][2] + t[0][3];
    s2 = t[0][4] + t[0][5] + t[0][6] + t[0][7];
    float mu = s * (1.0f / Dd);
    float var = s2 * (1.0f / Dd) - mu * mu;
    float rstd = rsqrtf(var + 1e-5f);
    const float4 g = ((const float4*)gamma)[tid];
    const float4 bb = ((const float4*)beta)[tid];
    union { unsigned us[2]; uint2 u2; } o;
    o.us[0] = pk2bf((v.x - mu) * rstd * g.x + bb.x, (v.y - mu) * rstd * g.y + bb.y);
    o.us[1] = pk2bf((v.z - mu) * rstd * g.z + bb.z, (v.w - mu) * rstd * g.w + bb.w);
    *(uint2*)(xn + (size_t)row * Dd + tid * 4) = o.u2;
  } else if (idx < 8192) {
    // ---- weight transpose
    int ti = idx - 4096;
    int z = ti >> 10, i = ti & 1023;
    const float* W = (z == 0) ? W0 : (z == 1) ? W1 : (z == 2) ? W2 : W3;
    u16* out = (z < 3) ? (o_qkv + (size_t)z * 1024 * 1024) : o_o;
    int k0 = (i & 31) * 32, n0 = (i >> 5) * 32;
    int tx = tid & 31, ty = tid >> 5;
#pragma unroll
    for (int j = 0; j < 4; ++j)
      t[ty + j * 8][tx] = W[(size_t)(k0 + ty + j * 8) * Dd + n0 + tx];
    __syncthreads();
#pragma unroll
    for (int j = 0; j < 4; ++j)
      out[(size_t)(n0 + ty + j * 8) * Dd + k0 + tx] = f2bf(t[tx][ty + j * 8]);
  } else if (idx < 9216) {
    // ---- mask bit-pack
    int m = idx - 8192;
    int b = m >> 9, rest = m & 511;
    int qw = rest >> 3, kblk = rest & 7;
    int k = kblk * 256 + tid;
    const int* mp = mask + ((size_t)b * Tq + qw * 32) * Tq + k;
    uint32_t wv = 0;
#pragma unroll
    for (int j = 0; j < 32; ++j) wv |= (mp[(size_t)j * Tq] ? 1u : 0u) << j;
    bits[((size_t)b * 64 + qw) * Tq + k] = wv;
  } else {
    // ---- bias concat
    int i = (idx - 9216) * 256 + tid;
    float v = (i < 1024) ? bq[i] : (i < 2048) ? bk[i - 1024] : bv[i - 2048];
    bias3[i] = v;
  }
}

// ------------------------------ merged Q|K + V^T GEMM (one 768-block dispatch)
// blocks [0,512):  Q|K: xn(4096x1024) x wt_qk(2048x1024)^T -> qkvb (ld 2048)
//                  bf16 = (acc + bias3[col]) * (col<1024 ? 0.125*log2e : 1)
// blocks [512,768): V^T: wt_v(1024x1024) x xn(4096x1024)^T -> vtb (ld 4096)
//                  bf16 = acc + bias3[2048+row]  (V lands pre-transposed)
__global__ __launch_bounds__(256) void qkvt_gemm(
    const u16* __restrict__ xn, const u16* __restrict__ wt,
    const float* __restrict__ bias3, u16* __restrict__ qkvb,
    u16* __restrict__ vtb) {
  __shared__ u16 As[128 * 32];
  __shared__ u16 Bs[128 * 32];
  int bid = blockIdx.x;
  bool vmode = bid >= 512;
  int m0, n0, ldc;
  const u16 *A, *Bt;
  u16* C;
  if (!vmode) {
    m0 = (bid >> 4) * 128; n0 = (bid & 15) * 128;
    A = xn; Bt = wt; C = qkvb; ldc = 2048;
  } else {
    int ti = bid - 512;
    m0 = (ti >> 5) * 128; n0 = (ti & 31) * 128;
    A = wt + (size_t)2 * 1024 * 1024; Bt = xn; C = vtb; ldc = 4096;
  }
  int tid = threadIdx.x;
  int lane = tid & 63, w = tid >> 6;
  int l16 = lane & 15, quad = lane >> 4;
  int wm = w >> 1, wn = w & 1;
  int srow = lane >> 2, scol = (lane & 3) << 3;
  const u16* ga0 = A + (size_t)(m0 + srow) * 1024 + scol;
  const u16* gb0 = Bt + (size_t)(n0 + srow) * 1024 + scol;
  f32x4 acc[4][4];
#pragma unroll
  for (int i = 0; i < 4; ++i)
#pragma unroll
    for (int j = 0; j < 4; ++j) acc[i][j] = {0.f, 0.f, 0.f, 0.f};

  for (int k0 = 0; k0 < 1024; k0 += 32) {
    __syncthreads();
#pragma unroll
    for (int c = 0; c < 2; ++c) {
      int rb = w * 32 + c * 16;
      load_lds16(ga0 + (size_t)rb * 1024 + k0, (char*)As + rb * 64);
      load_lds16(gb0 + (size_t)rb * 1024 + k0, (char*)Bs + rb * 64);
    }
    __syncthreads();
    short8 af[4], bf[4];
#pragma unroll
    for (int mt = 0; mt < 4; ++mt)
      af[mt] = *(const short8*)&As[(wm * 64 + mt * 16 + l16) * 32 + quad * 8];
#pragma unroll
    for (int nt = 0; nt < 4; ++nt)
      bf[nt] = *(const short8*)&Bs[(wn * 64 + nt * 16 + l16) * 32 + quad * 8];
#pragma unroll
    for (int mt = 0; mt < 4; ++mt)
#pragma unroll
      for (int nt = 0; nt < 4; ++nt)
        acc[mt][nt] = mfma16(af[mt], bf[nt], acc[mt][nt]);
  }
#pragma unroll
  for (int nt = 0; nt < 4; ++nt) {
    int col = n0 + wn * 64 + nt * 16 + l16;
    float bcol = vmode ? 0.f : bias3[col];
    float scl = (!vmode && col < 1024) ? 0.18033688011112042f : 1.0f;
#pragma unroll
    for (int mt = 0; mt < 4; ++mt) {
#pragma unroll
      for (int r = 0; r < 4; ++r) {
        int row = m0 + wm * 64 + mt * 16 + quad * 4 + r;
        float bv = vmode ? bias3[2048 + row] : bcol;
        C[(size_t)row * ldc + col] = f2bf((acc[mt][nt][r] + bv) * scl);
      }
    }
  }
}

// --------------------------------------------- GEMM: C = A * Bt^T (+ epi)
// Out-projection: fp32 C = acc + bias[col] + resid. MT=64, N-tile 128.
template <int MT>
__global__ __launch_bounds__(256) void gemm_bt(
    const u16* __restrict__ A, const u16* __restrict__ Bt,
    const float* __restrict__ bias, const float* __restrict__ resid,
    float* __restrict__ Cout, int ldc, int K) {
  constexpr int MTI = MT / 32;       // mfma row-tiles per wave
  constexpr int ACALLS = MT / 64;    // 16-row staging calls per wave for A
  __shared__ u16 As[MT * 32];
  __shared__ u16 Bs[128 * 32];
  int tid = threadIdx.x;
  int lane = tid & 63, w = tid >> 6;
  int l16 = lane & 15, quad = lane >> 4;
  int wm = w >> 1, wn = w & 1;
  int m0 = blockIdx.y * MT, n0 = blockIdx.x * 128;
  int srow = lane >> 2, scol = (lane & 3) << 3;
  const u16* ga0 = A + (size_t)(m0 + srow) * K + scol;
  const u16* gb0 = Bt + (size_t)(n0 + srow) * K + scol;
  f32x4 acc[MTI][4];
#pragma unroll
  for (int i = 0; i < MTI; ++i)
#pragma unroll
    for (int j = 0; j < 4; ++j) acc[i][j] = {0.f, 0.f, 0.f, 0.f};

  for (int k0 = 0; k0 < K; k0 += 32) {
    __syncthreads();
#pragma unroll
    for (int c = 0; c < ACALLS; ++c) {
      int rb = w * (MT / 4) + c * 16;
      load_lds16(ga0 + (size_t)rb * K + k0, (char*)As + rb * 64);
    }
#pragma unroll
    for (int c = 0; c < 2; ++c) {
      int rb = w * 32 + c * 16;
      load_lds16(gb0 + (size_t)rb * K + k0, (char*)Bs + rb * 64);
    }
    __syncthreads();
    short8 af[MTI], bf[4];
#pragma unroll
    for (int mt = 0; mt < MTI; ++mt)
      af[mt] = *(const short8*)&As[(wm * (MT / 2) + mt * 16 + l16) * 32 + quad * 8];
#pragma unroll
    for (int nt = 0; nt < 4; ++nt)
      bf[nt] = *(const short8*)&Bs[(wn * 64 + nt * 16 + l16) * 32 + quad * 8];
#pragma unroll
    for (int mt = 0; mt < MTI; ++mt)
#pragma unroll
      for (int nt = 0; nt < 4; ++nt)
        acc[mt][nt] = mfma16(af[mt], bf[nt], acc[mt][nt]);
  }
#pragma unroll
  for (int nt = 0; nt < 4; ++nt) {
    int col = n0 + wn * 64 + nt * 16 + l16;
    float bv = bias[col];
#pragma unroll
    for (int mt = 0; mt < MTI; ++mt) {
#pragma unroll
      for (int r = 0; r < 4; ++r) {
        int row = m0 + wm * (MT / 2) + mt * 16 + quad * 4 + r;
        size_t idx = (size_t)row * ldc + col;
        Cout[idx] = acc[mt][nt][r] + bv + resid[idx];
      }
    }
  }
}

// ----------------------------------------------------- flash attention
// 8-wave shared-tile rework of the R7 champion: block = 128 q x one (b,h),
// 8 waves x 16 q SHARING the same K/V LDS tiles (K/V are q-independent).
// Grid 16x16x2 = 512 blocks x 512 threads; LDS still 40 KB -> 4 blocks/CU
// = 2048 threads/CU (device max) = 32 waves/CU, 2x the R7 config's 16.
// VGPR 60 <= 64 keeps 8 waves/SIMD legal (launch_bounds(512,8) pins it).
// Per-wave inner code is byte-identical to R7 (T15 pipeline: QK(t),
// PV(t-1), SM(t); K dbuf, V tri-buf; base-2 softmax, bfe mask, permlane
// P-redistribution, MFMA row sums, setprio around MFMA clusters). Only
// the staging row-split changed: waves 0-3 stage K (16 rows each),
// waves 4-7 stage V.
__global__ __launch_bounds__(512, 8) void attn_kernel(
    const u16* __restrict__ qkv, const u16* __restrict__ vt,
    const uint32_t* __restrict__ mbits, u16* __restrict__ ybuf) {
  __shared__ u16 Ks[2][64 * 64];
  __shared__ u16 Vs[3][64 * 64];
  int tid = threadIdx.x;
  int lane = tid & 63, w = tid >> 6;  // 8 waves
  int l16 = lane & 15, quad = lane >> 4;
  int x7 = l16 & 7;
  int qt = blockIdx.x, h = blockIdx.y, b = blockIdx.z;
  int qbase = qt * 128 + w * 16;
  const u16* Qb = qkv + (size_t)b * Tq * 2048 + h * 64;
  const u16* Kb = Qb + 1024;
  const u16* Vb = vt + (size_t)(h * 64) * 4096 + b * 2048;
  const uint32_t* Mrow = mbits + ((size_t)b * 64 + (qbase >> 5)) * Tq;
  int shift = (qbase & 31) + l16;  // this lane's query bit within the mask word

  int rowb = (w & 3) * 16;  // this wave's 16-row staging slice
  int r8 = lane >> 3;
  int phys = lane & 7;
  int chunk = phys ^ r8;
  bool isK = (w < 4);

  short8 qf[2];
#pragma unroll
  for (int ks = 0; ks < 2; ++ks)
    qf[ks] = *(const short8*)&Qb[(size_t)(qbase + l16) * 2048 + ks * 32 + quad * 8];

  const short8 vones = {0x3F80, 0x3F80, 0x3F80, 0x3F80,
                        0x3F80, 0x3F80, 0x3F80, 0x3F80};  // bf16 1.0

  f32x4 acc[4];
#pragma unroll
  for (int j = 0; j < 4; ++j) acc[j] = {0.f, 0.f, 0.f, 0.f};
  f32x4 acc_s = {0.f, 0.f, 0.f, 0.f};  // per-query P row sums (via MFMA)

  // waves 0-3 stage K(tile)->Ks[kb]; waves 4-7 stage V(tile)->Vs[vb];
  // each wave covers rows rowb + {0,8} + r8 (16 of the 64 tile rows).
  auto stage = [&](int kb, int vb, int k0) {
    if (isK) {
#pragma unroll
      for (int j = 0; j < 2; ++j)
        load_lds16(Kb + (size_t)(k0 + rowb + j * 8 + r8) * 2048 + chunk * 8,
                   (char*)&Ks[kb][0] + (rowb + j * 8) * 128);
    } else {
#pragma unroll
      for (int j = 0; j < 2; ++j)
        load_lds16(Vb + (size_t)(rowb + j * 8 + r8) * 4096 + k0 + chunk * 8,
                   (char*)&Vs[vb][0] + (rowb + j * 8) * 128);
    }
  };

  auto ldmask = [&](int k0, uint32_t (&mv)[4][4]) {
#pragma unroll
    for (int mt = 0; mt < 4; ++mt) {
      uint4 m4 = *(const uint4*)&Mrow[k0 + mt * 16 + quad * 4];
      mv[mt][0] = m4.x; mv[mt][1] = m4.y; mv[mt][2] = m4.z; mv[mt][3] = m4.w;
    }
  };

  // S^T = K * Qs^T  (rows = keys, cols = queries)
  auto qk = [&](const u16* Kt, f32x4 (&s)[4]) {
#pragma unroll
    for (int i = 0; i < 4; ++i) s[i] = {0.f, 0.f, 0.f, 0.f};
#pragma unroll
    for (int mt = 0; mt < 4; ++mt)
#pragma unroll
      for (int ks = 0; ks < 2; ++ks) {
        short8 kf = *(const short8*)&Kt[(mt * 16 + l16) * 64 +
                                        (((ks << 2) | quad) ^ x7) * 8];
        s[mt] = mfma16(kf, qf[ks], s[mt]);
      }
  };

  // p = exp2(s); mask via v_bfe_i32 sign-extend + AND (masked -> +0);
  // pack to bf16 pairs, then permlane-redistribute into the PV A-fragment.
  auto softmax_pack = [&](f32x4 (&s)[4], uint32_t (&mv)[4][4],
                          short8 (&pfo)[2]) {
    unsigned c[4][2];
#pragma unroll
    for (int mt = 0; mt < 4; ++mt) {
      float p[4];
#pragma unroll
      for (int r = 0; r < 4; ++r) {
        float e = __builtin_amdgcn_exp2f(s[mt][r]);
        int keep = __builtin_amdgcn_sbfe((int)mv[mt][r], (unsigned)shift, 1u);
        union { float f; int i; } u; u.f = e; u.i &= keep;
        p[r] = u.f;
      }
      c[mt][0] = pk2bf(p[0], p[1]);
      c[mt][1] = pk2bf(p[2], p[3]);
    }
#pragma unroll
    for (int ks = 0; ks < 2; ++ks) {
      union { unsigned u[4]; short8 s8; } P;
#pragma unroll
      for (int hh = 0; hh < 2; ++hh) {
        unsigned xx = c[2 * ks][hh], yy = c[2 * ks + 1][hh];
        permswap(xx, yy);
        P.u[hh] = xx;      // keys quad*8 + {2hh, 2hh+1}
        P.u[2 + hh] = yy;  // keys quad*8 + 4 + {2hh, 2hh+1}
      }
      pfo[ks] = P.s8;
    }
  };

  // row sums + y += P * V
  auto pv = [&](const u16* Vtile, short8 (&pf)[2]) {
    acc_s = mfma16(pf[0], vones, acc_s);
    acc_s = mfma16(pf[1], vones, acc_s);
#pragma unroll
    for (int ks = 0; ks < 2; ++ks)
#pragma unroll
      for (int nt2 = 0; nt2 < 4; ++nt2) {
        short8 vf = *(const short8*)&Vtile[(nt2 * 16 + l16) * 64 +
                                           (((ks << 2) | quad) ^ x7) * 8];
        acc[nt2] = mfma16(pf[ks], vf, acc[nt2]);
      }
  };

  // ---- prologue: tile 0 (QK + SM only; PV deferred)
  stage(0, 0, 0);
  __syncthreads();
  uint32_t mv[4][4];
  f32x4 s[4];
  short8 pfp[2];
  ldmask(0, mv);
  stage(1, 1, 64);
  __builtin_amdgcn_s_setprio(1);
  qk(Ks[0], s);
  __builtin_amdgcn_s_setprio(0);
  softmax_pack(s, mv, pfp);

  // ---- pipelined main loop
  for (int kt = 1; kt < 32; ++kt) {
    int k0 = kt * 64;
    __syncthreads();
    ldmask(k0, mv);
    if (kt < 31) stage((kt + 1) & 1, (kt + 1) % 3, k0 + 64);
    __builtin_amdgcn_s_setprio(1);
    qk(Ks[kt & 1], s);          // QK(t)
    pv(Vs[(kt - 1) % 3], pfp);  // PV(t-1): independent of QK(t)
    __builtin_amdgcn_s_setprio(0);
    short8 pfc[2];
    softmax_pack(s, mv, pfc);   // SM(t): overlaps in-flight PV MFMAs
    pfp[0] = pfc[0];
    pfp[1] = pfc[1];
  }
  // ---- drain: PV(31)  (31 % 3 == 1; staged at kt=30, synced at kt=31)
  __builtin_amdgcn_s_setprio(1);
  pv(Vs[1], pfp);
  __builtin_amdgcn_s_setprio(0);

  // epilogue: normalize by row sum, store bf16 to ybuf[row][h*64+dh]
#pragma unroll
  for (int r = 0; r < 4; ++r) {
    float li = 1.0f / acc_s[r];
    size_t row = (size_t)b * Tq + qbase + quad * 4 + r;
#pragma unroll
    for (int nt2 = 0; nt2 < 4; ++nt2)
      ybuf[row * Dd + h * 64 + nt2 * 16 + l16] = f2bf(acc[nt2][r] * li);
  }
}

// ---------------------------------------------------------------- launcher
extern "C" void kernel_launch(void* const* d_in, const int* in_sizes, int n_in,
                              void* d_out, int out_size, void* d_ws, size_t ws_size,
                              hipStream_t stream) {
  (void)in_sizes; (void)n_in; (void)out_size; (void)ws_size;
  const float* x = (const float*)d_in[0];
  const int* mask = (const int*)d_in[1];
  const float* gamma = (const float*)d_in[2];
  const float* beta = (const float*)d_in[3];
  const float* Wq = (const float*)d_in[4];
  const float* bq = (const float*)d_in[5];
  const float* Wk = (const float*)d_in[6];
  const float* bk = (const float*)d_in[7];
  const float* Wv = (const float*)d_in[8];
  const float* bv = (const float*)d_in[9];
  const float* Wo = (const float*)d_in[10];
  const float* bo = (const float*)d_in[11];
  float* out = (float*)d_out;
  char* ws = (char*)d_ws;

  constexpr size_t SZ_XN = (size_t)4096 * 1024 * 2;
  constexpr size_t SZ_WTQ = (size_t)3072 * 1024 * 2;
  constexpr size_t SZ_WOT = (size_t)1024 * 1024 * 2;
  constexpr size_t SZ_B3 = 3072 * 4;
  constexpr size_t SZ_QKV = (size_t)4096 * 2048 * 2;   // Q|K only (ld 2048)
  constexpr size_t SZ_MBITS = (size_t)2 * 64 * 2048 * 4;
  constexpr size_t SZ_VT = (size_t)1024 * 4096 * 2;    // V^T (ld 4096)
  size_t off = 0;
  u16* xn = (u16*)(ws + off); off += SZ_XN;
  u16* wtqkv = (u16*)(ws + off); off += SZ_WTQ;
  u16* wot = (u16*)(ws + off); off += SZ_WOT;
  float* bias3 = (float*)(ws + off); off += SZ_B3;
  u16* qkvb = (u16*)(ws + off); off += SZ_QKV;
  uint32_t* mbits = (uint32_t*)(ws + off); off += SZ_MBITS;
  u16* vtb = (u16*)(ws + off); off += SZ_VT;
  u16* ybuf = (u16*)(ws + off);

  prep_kernel<<<dim3(9228), dim3(256), 0, stream>>>(
      x, gamma, beta, xn, Wq, Wk, Wv, Wo, wtqkv, wot, mask, mbits, bq, bk, bv,
      bias3);
  qkvt_gemm<<<dim3(768), dim3(256), 0, stream>>>(xn, wtqkv, bias3, qkvb, vtb);
  attn_kernel<<<dim3(16, 16, 2), dim3(512), 0, stream>>>(qkvb, vtb, mbits, ybuf);
  gemm_bt<64><<<dim3(8, 64), dim3(256), 0, stream>>>(
      ybuf, wot, bo, x, out, 1024, 1024);
}

// Round 13
// 237.809 us; speedup vs baseline: 2.2105x; 2.2105x over previous
//
#include <hip/hip_runtime.h>
#include <hip/hip_bf16.h>
#include <stdint.h>

// Problem constants: B=2, T=2048, D=1024, H=16, dh=64
#define Tq 2048
#define Dd 1024
#define Hh 16

typedef unsigned short u16;
typedef __attribute__((ext_vector_type(8))) short short8;
typedef __attribute__((ext_vector_type(4))) float f32x4;

__device__ __forceinline__ u16 f2bf(float f) {
  union { float f; unsigned u; } v; v.f = f;
  unsigned r = (v.u + 0x7fffu + ((v.u >> 16) & 1u)) >> 16;  // RNE
  return (u16)r;
}

__device__ __forceinline__ unsigned pk2bf(float a, float b) {
  __hip_bfloat162 h = __float22bfloat162_rn(float2{a, b});
  union { __hip_bfloat162 h; unsigned u; } c; c.h = h;
  return c.u;
}

__device__ __forceinline__ void load_lds16(const void* g, void* l) {
  __builtin_amdgcn_global_load_lds(
      (const __attribute__((address_space(1))) unsigned*)g,
      (__attribute__((address_space(3))) unsigned*)l, 16, 0, 0);
}

__device__ __forceinline__ f32x4 mfma16(short8 a, short8 b, f32x4 c) {
  return __builtin_amdgcn_mfma_f32_16x16x32_bf16(a, b, c, 0, 0, 0);
}

// Cross-lane word redistribution for the PV A-fragment. Builtins preferred:
// the compiler's hazard recognizer inserts the DPP-read wait states that a
// raw asm block does not get (round-2 failure: sporadic stale lanes).
__device__ __forceinline__ void permswap(unsigned& xx, unsigned& yy) {
#if __has_builtin(__builtin_amdgcn_permlane32_swap) && \
    __has_builtin(__builtin_amdgcn_permlane16_swap)
  typedef __attribute__((ext_vector_type(2))) unsigned uint2v;
  uint2v t0 = __builtin_amdgcn_permlane32_swap(xx, yy, false, false);
  uint2v t1 = __builtin_amdgcn_permlane16_swap(t0[0], t0[1], false, false);
  xx = t1[0];
  yy = t1[1];
#else
  asm volatile(
      "s_nop 1\n\t"
      "v_permlane32_swap_b32 %0, %1\n\t"
      "s_nop 1\n\t"
      "v_permlane16_swap_b32 %0, %1\n\t"
      "s_nop 1"
      : "+v"(xx), "+v"(yy));
#endif
}

// ------------------------------------------------------------- fused prep
// blocks [0,4096): LayerNorm rows
// blocks [4096,8192): 4x weight transpose (KxN fp32 -> NxK bf16)
// blocks [8192,9216): mask bit-pack (b,q,k)->bits[b][q/32][k]
// blocks [9216,9228): bias concat
__global__ __launch_bounds__(256) void prep_kernel(
    const float* __restrict__ x, const float* __restrict__ gamma,
    const float* __restrict__ beta, u16* __restrict__ xn,
    const float* __restrict__ W0, const float* __restrict__ W1,
    const float* __restrict__ W2, const float* __restrict__ W3,
    u16* __restrict__ o_qkv, u16* __restrict__ o_o,
    const int* __restrict__ mask, uint32_t* __restrict__ bits,
    const float* __restrict__ bq, const float* __restrict__ bk,
    const float* __restrict__ bv, float* __restrict__ bias3) {
  __shared__ float t[32][33];
  int idx = blockIdx.x;
  int tid = threadIdx.x;
  if (idx < 4096) {
    // ---- LayerNorm
    int row = idx;
    const float4 v = ((const float4*)(x + (size_t)row * Dd))[tid];
    float s = v.x + v.y + v.z + v.w;
    float s2 = v.x * v.x + v.y * v.y + v.z * v.z + v.w * v.w;
#pragma unroll
    for (int off = 1; off < 64; off <<= 1) {
      s += __shfl_xor(s, off);
      s2 += __shfl_xor(s2, off);
    }
    int w = tid >> 6;
    if ((tid & 63) == 0) { t[0][w] = s; t[0][4 + w] = s2; }
    __syncthreads();
    s = t[0][0] + t[0][1] + t[0][2] + t[0][3];
    s2 = t[0][4] + t[0][5] + t[0][6] + t[0][7];
    float mu = s * (1.0f / Dd);
    float var = s2 * (1.0f / Dd) - mu * mu;
    float rstd = rsqrtf(var + 1e-5f);
    const float4 g = ((const float4*)gamma)[tid];
    const float4 bb = ((const float4*)beta)[tid];
    union { unsigned us[2]; uint2 u2; } o;
    o.us[0] = pk2bf((v.x - mu) * rstd * g.x + bb.x, (v.y - mu) * rstd * g.y + bb.y);
    o.us[1] = pk2bf((v.z - mu) * rstd * g.z + bb.z, (v.w - mu) * rstd * g.w + bb.w);
    *(uint2*)(xn + (size_t)row * Dd + tid * 4) = o.u2;
  } else if (idx < 8192) {
    // ---- weight transpose
    int ti = idx - 4096;
    int z = ti >> 10, i = ti & 1023;
    const float* W = (z == 0) ? W0 : (z == 1) ? W1 : (z == 2) ? W2 : W3;
    u16* out = (z < 3) ? (o_qkv + (size_t)z * 1024 * 1024) : o_o;
    int k0 = (i & 31) * 32, n0 = (i >> 5) * 32;
    int tx = tid & 31, ty = tid >> 5;
#pragma unroll
    for (int j = 0; j < 4; ++j)
      t[ty + j * 8][tx] = W[(size_t)(k0 + ty + j * 8) * Dd + n0 + tx];
    __syncthreads();
#pragma unroll
    for (int j = 0; j < 4; ++j)
      out[(size_t)(n0 + ty + j * 8) * Dd + k0 + tx] = f2bf(t[tx][ty + j * 8]);
  } else if (idx < 9216) {
    // ---- mask bit-pack
    int m = idx - 8192;
    int b = m >> 9, rest = m & 511;
    int qw = rest >> 3, kblk = rest & 7;
    int k = kblk * 256 + tid;
    const int* mp = mask + ((size_t)b * Tq + qw * 32) * Tq + k;
    uint32_t wv = 0;
#pragma unroll
    for (int j = 0; j < 32; ++j) wv |= (mp[(size_t)j * Tq] ? 1u : 0u) << j;
    bits[((size_t)b * 64 + qw) * Tq + k] = wv;
  } else {
    // ---- bias concat
    int i = (idx - 9216) * 256 + tid;
    float v = (i < 1024) ? bq[i] : (i < 2048) ? bk[i - 1024] : bv[i - 2048];
    bias3[i] = v;
  }
}

// ------------------------------ merged Q|K + V^T GEMM (one 768-block dispatch)
// blocks [0,512):  Q|K: xn(4096x1024) x wt_qk(2048x1024)^T -> qkvb (ld 2048)
//                  bf16 = (acc + bias3[col]) * (col<1024 ? 0.125*log2e : 1)
// blocks [512,768): V^T: wt_v(1024x1024) x xn(4096x1024)^T -> vtb (ld 4096)
//                  bf16 = acc + bias3[2048+row]  (V lands pre-transposed)
__global__ __launch_bounds__(256) void qkvt_gemm(
    const u16* __restrict__ xn, const u16* __restrict__ wt,
    const float* __restrict__ bias3, u16* __restrict__ qkvb,
    u16* __restrict__ vtb) {
  __shared__ u16 As[128 * 32];
  __shared__ u16 Bs[128 * 32];
  int bid = blockIdx.x;
  bool vmode = bid >= 512;
  int m0, n0, ldc;
  const u16 *A, *Bt;
  u16* C;
  if (!vmode) {
    m0 = (bid >> 4) * 128; n0 = (bid & 15) * 128;
    A = xn; Bt = wt; C = qkvb; ldc = 2048;
  } else {
    int ti = bid - 512;
    m0 = (ti >> 5) * 128; n0 = (ti & 31) * 128;
    A = wt + (size_t)2 * 1024 * 1024; Bt = xn; C = vtb; ldc = 4096;
  }
  int tid = threadIdx.x;
  int lane = tid & 63, w = tid >> 6;
  int l16 = lane & 15, quad = lane >> 4;
  int wm = w >> 1, wn = w & 1;
  int srow = lane >> 2, scol = (lane & 3) << 3;
  const u16* ga0 = A + (size_t)(m0 + srow) * 1024 + scol;
  const u16* gb0 = Bt + (size_t)(n0 + srow) * 1024 + scol;
  f32x4 acc[4][4];
#pragma unroll
  for (int i = 0; i < 4; ++i)
#pragma unroll
    for (int j = 0; j < 4; ++j) acc[i][j] = {0.f, 0.f, 0.f, 0.f};

  for (int k0 = 0; k0 < 1024; k0 += 32) {
    __syncthreads();
#pragma unroll
    for (int c = 0; c < 2; ++c) {
      int rb = w * 32 + c * 16;
      load_lds16(ga0 + (size_t)rb * 1024 + k0, (char*)As + rb * 64);
      load_lds16(gb0 + (size_t)rb * 1024 + k0, (char*)Bs + rb * 64);
    }
    __syncthreads();
    short8 af[4], bf[4];
#pragma unroll
    for (int mt = 0; mt < 4; ++mt)
      af[mt] = *(const short8*)&As[(wm * 64 + mt * 16 + l16) * 32 + quad * 8];
#pragma unroll
    for (int nt = 0; nt < 4; ++nt)
      bf[nt] = *(const short8*)&Bs[(wn * 64 + nt * 16 + l16) * 32 + quad * 8];
#pragma unroll
    for (int mt = 0; mt < 4; ++mt)
#pragma unroll
      for (int nt = 0; nt < 4; ++nt)
        acc[mt][nt] = mfma16(af[mt], bf[nt], acc[mt][nt]);
  }
#pragma unroll
  for (int nt = 0; nt < 4; ++nt) {
    int col = n0 + wn * 64 + nt * 16 + l16;
    float bcol = vmode ? 0.f : bias3[col];
    float scl = (!vmode && col < 1024) ? 0.18033688011112042f : 1.0f;
#pragma unroll
    for (int mt = 0; mt < 4; ++mt) {
#pragma unroll
      for (int r = 0; r < 4; ++r) {
        int row = m0 + wm * 64 + mt * 16 + quad * 4 + r;
        float bv = vmode ? bias3[2048 + row] : bcol;
        C[(size_t)row * ldc + col] = f2bf((acc[mt][nt][r] + bv) * scl);
      }
    }
  }
}

// --------------------------------------------- GEMM: C = A * Bt^T (+ epi)
// Out-projection: fp32 C = acc + bias[col] + resid. MT=64, N-tile 128.
template <int MT>
__global__ __launch_bounds__(256) void gemm_bt(
    const u16* __restrict__ A, const u16* __restrict__ Bt,
    const float* __restrict__ bias, const float* __restrict__ resid,
    float* __restrict__ Cout, int ldc, int K) {
  constexpr int MTI = MT / 32;       // mfma row-tiles per wave
  constexpr int ACALLS = MT / 64;    // 16-row staging calls per wave for A
  __shared__ u16 As[MT * 32];
  __shared__ u16 Bs[128 * 32];
  int tid = threadIdx.x;
  int lane = tid & 63, w = tid >> 6;
  int l16 = lane & 15, quad = lane >> 4;
  int wm = w >> 1, wn = w & 1;
  int m0 = blockIdx.y * MT, n0 = blockIdx.x * 128;
  int srow = lane >> 2, scol = (lane & 3) << 3;
  const u16* ga0 = A + (size_t)(m0 + srow) * K + scol;
  const u16* gb0 = Bt + (size_t)(n0 + srow) * K + scol;
  f32x4 acc[MTI][4];
#pragma unroll
  for (int i = 0; i < MTI; ++i)
#pragma unroll
    for (int j = 0; j < 4; ++j) acc[i][j] = {0.f, 0.f, 0.f, 0.f};

  for (int k0 = 0; k0 < K; k0 += 32) {
    __syncthreads();
#pragma unroll
    for (int c = 0; c < ACALLS; ++c) {
      int rb = w * (MT / 4) + c * 16;
      load_lds16(ga0 + (size_t)rb * K + k0, (char*)As + rb * 64);
    }
#pragma unroll
    for (int c = 0; c < 2; ++c) {
      int rb = w * 32 + c * 16;
      load_lds16(gb0 + (size_t)rb * K + k0, (char*)Bs + rb * 64);
    }
    __syncthreads();
    short8 af[MTI], bf[4];
#pragma unroll
    for (int mt = 0; mt < MTI; ++mt)
      af[mt] = *(const short8*)&As[(wm * (MT / 2) + mt * 16 + l16) * 32 + quad * 8];
#pragma unroll
    for (int nt = 0; nt < 4; ++nt)
      bf[nt] = *(const short8*)&Bs[(wn * 64 + nt * 16 + l16) * 32 + quad * 8];
#pragma unroll
    for (int mt = 0; mt < MTI; ++mt)
#pragma unroll
      for (int nt = 0; nt < 4; ++nt)
        acc[mt][nt] = mfma16(af[mt], bf[nt], acc[mt][nt]);
  }
#pragma unroll
  for (int nt = 0; nt < 4; ++nt) {
    int col = n0 + wn * 64 + nt * 16 + l16;
    float bv = bias[col];
#pragma unroll
    for (int mt = 0; mt < MTI; ++mt) {
#pragma unroll
      for (int r = 0; r < 4; ++r) {
        int row = m0 + wm * (MT / 2) + mt * 16 + quad * 4 + r;
        size_t idx = (size_t)row * ldc + col;
        Cout[idx] = acc[mt][nt][r] + bv + resid[idx];
      }
    }
  }
}

// ----------------------------------------------------- flash attention
// 8-wave shared-tile (R12 geometry, launch-bounds FIXED): block = 128 q x
// one (b,h), 8 waves x 16 q sharing the same K/V LDS tiles. Grid 16x16x2
// = 512 blocks x 512 threads; LDS 40 KB -> 4 blocks/CU = 32 waves/CU.
// R12's __launch_bounds__(512,8) capped the unified VGPR+AGPR file at 64
// regs/wave -> VGPR_Count 32 + total spill (FETCH 688 MB, 344 us). (512,4)
// caps at 128: the natural ~60-VGPR allocation fits, no spill, and the
// HARDWARE still reaches 8 waves/SIMD because 60 <= 64.
// Per-wave inner code identical to the R7 champion (T15 pipeline, base-2
// softmax, bfe mask, permlane P-redistribution, MFMA row sums, setprio).
__global__ __launch_bounds__(512, 4) void attn_kernel(
    const u16* __restrict__ qkv, const u16* __restrict__ vt,
    const uint32_t* __restrict__ mbits, u16* __restrict__ ybuf) {
  __shared__ u16 Ks[2][64 * 64];
  __shared__ u16 Vs[3][64 * 64];
  int tid = threadIdx.x;
  int lane = tid & 63, w = tid >> 6;  // 8 waves
  int l16 = lane & 15, quad = lane >> 4;
  int x7 = l16 & 7;
  int qt = blockIdx.x, h = blockIdx.y, b = blockIdx.z;
  int qbase = qt * 128 + w * 16;
  const u16* Qb = qkv + (size_t)b * Tq * 2048 + h * 64;
  const u16* Kb = Qb + 1024;
  const u16* Vb = vt + (size_t)(h * 64) * 4096 + b * 2048;
  const uint32_t* Mrow = mbits + ((size_t)b * 64 + (qbase >> 5)) * Tq;
  int shift = (qbase & 31) + l16;  // this lane's query bit within the mask word

  int rowb = (w & 3) * 16;  // this wave's 16-row staging slice
  int r8 = lane >> 3;
  int phys = lane & 7;
  int chunk = phys ^ r8;
  bool isK = (w < 4);

  short8 qf[2];
#pragma unroll
  for (int ks = 0; ks < 2; ++ks)
    qf[ks] = *(const short8*)&Qb[(size_t)(qbase + l16) * 2048 + ks * 32 + quad * 8];

  const short8 vones = {0x3F80, 0x3F80, 0x3F80, 0x3F80,
                        0x3F80, 0x3F80, 0x3F80, 0x3F80};  // bf16 1.0

  f32x4 acc[4];
#pragma unroll
  for (int j = 0; j < 4; ++j) acc[j] = {0.f, 0.f, 0.f, 0.f};
  f32x4 acc_s = {0.f, 0.f, 0.f, 0.f};  // per-query P row sums (via MFMA)

  // waves 0-3 stage K(tile)->Ks[kb]; waves 4-7 stage V(tile)->Vs[vb];
  // each wave covers rows rowb + {0,8} + r8 (16 of the 64 tile rows).
  auto stage = [&](int kb, int vb, int k0) {
    if (isK) {
#pragma unroll
      for (int j = 0; j < 2; ++j)
        load_lds16(Kb + (size_t)(k0 + rowb + j * 8 + r8) * 2048 + chunk * 8,
                   (char*)&Ks[kb][0] + (rowb + j * 8) * 128);
    } else {
#pragma unroll
      for (int j = 0; j < 2; ++j)
        load_lds16(Vb + (size_t)(rowb + j * 8 + r8) * 4096 + k0 + chunk * 8,
                   (char*)&Vs[vb][0] + (rowb + j * 8) * 128);
    }
  };

  auto ldmask = [&](int k0, uint32_t (&mv)[4][4]) {
#pragma unroll
    for (int mt = 0; mt < 4; ++mt) {
      uint4 m4 = *(const uint4*)&Mrow[k0 + mt * 16 + quad * 4];
      mv[mt][0] = m4.x; mv[mt][1] = m4.y; mv[mt][2] = m4.z; mv[mt][3] = m4.w;
    }
  };

  // S^T = K * Qs^T  (rows = keys, cols = queries)
  auto qk = [&](const u16* Kt, f32x4 (&s)[4]) {
#pragma unroll
    for (int i = 0; i < 4; ++i) s[i] = {0.f, 0.f, 0.f, 0.f};
#pragma unroll
    for (int mt = 0; mt < 4; ++mt)
#pragma unroll
      for (int ks = 0; ks < 2; ++ks) {
        short8 kf = *(const short8*)&Kt[(mt * 16 + l16) * 64 +
                                        (((ks << 2) | quad) ^ x7) * 8];
        s[mt] = mfma16(kf, qf[ks], s[mt]);
      }
  };

  // p = exp2(s); mask via v_bfe_i32 sign-extend + AND (masked -> +0);
  // pack to bf16 pairs, then permlane-redistribute into the PV A-fragment.
  auto softmax_pack = [&](f32x4 (&s)[4], uint32_t (&mv)[4][4],
                          short8 (&pfo)[2]) {
    unsigned c[4][2];
#pragma unroll
    for (int mt = 0; mt < 4; ++mt) {
      float p[4];
#pragma unroll
      for (int r = 0; r < 4; ++r) {
        float e = __builtin_amdgcn_exp2f(s[mt][r]);
        int keep = __builtin_amdgcn_sbfe((int)mv[mt][r], (unsigned)shift, 1u);
        union { float f; int i; } u; u.f = e; u.i &= keep;
        p[r] = u.f;
      }
      c[mt][0] = pk2bf(p[0], p[1]);
      c[mt][1] = pk2bf(p[2], p[3]);
    }
#pragma unroll
    for (int ks = 0; ks < 2; ++ks) {
      union { unsigned u[4]; short8 s8; } P;
#pragma unroll
      for (int hh = 0; hh < 2; ++hh) {
        unsigned xx = c[2 * ks][hh], yy = c[2 * ks + 1][hh];
        permswap(xx, yy);
        P.u[hh] = xx;      // keys quad*8 + {2hh, 2hh+1}
        P.u[2 + hh] = yy;  // keys quad*8 + 4 + {2hh, 2hh+1}
      }
      pfo[ks] = P.s8;
    }
  };

  // row sums + y += P * V
  auto pv = [&](const u16* Vtile, short8 (&pf)[2]) {
    acc_s = mfma16(pf[0], vones, acc_s);
    acc_s = mfma16(pf[1], vones, acc_s);
#pragma unroll
    for (int ks = 0; ks < 2; ++ks)
#pragma unroll
      for (int nt2 = 0; nt2 < 4; ++nt2) {
        short8 vf = *(const short8*)&Vtile[(nt2 * 16 + l16) * 64 +
                                           (((ks << 2) | quad) ^ x7) * 8];
        acc[nt2] = mfma16(pf[ks], vf, acc[nt2]);
      }
  };

  // ---- prologue: tile 0 (QK + SM only; PV deferred)
  stage(0, 0, 0);
  __syncthreads();
  uint32_t mv[4][4];
  f32x4 s[4];
  short8 pfp[2];
  ldmask(0, mv);
  stage(1, 1, 64);
  __builtin_amdgcn_s_setprio(1);
  qk(Ks[0], s);
  __builtin_amdgcn_s_setprio(0);
  softmax_pack(s, mv, pfp);

  // ---- pipelined main loop
  for (int kt = 1; kt < 32; ++kt) {
    int k0 = kt * 64;
    __syncthreads();
    ldmask(k0, mv);
    if (kt < 31) stage((kt + 1) & 1, (kt + 1) % 3, k0 + 64);
    __builtin_amdgcn_s_setprio(1);
    qk(Ks[kt & 1], s);          // QK(t)
    pv(Vs[(kt - 1) % 3], pfp);  // PV(t-1): independent of QK(t)
    __builtin_amdgcn_s_setprio(0);
    short8 pfc[2];
    softmax_pack(s, mv, pfc);   // SM(t): overlaps in-flight PV MFMAs
    pfp[0] = pfc[0];
    pfp[1] = pfc[1];
  }
  // ---- drain: PV(31)  (31 % 3 == 1; staged at kt=30, synced at kt=31)
  __builtin_amdgcn_s_setprio(1);
  pv(Vs[1], pfp);
  __builtin_amdgcn_s_setprio(0);

  // epilogue: normalize by row sum, store bf16 to ybuf[row][h*64+dh]
#pragma unroll
  for (int r = 0; r < 4; ++r) {
    float li = 1.0f / acc_s[r];
    size_t row = (size_t)b * Tq + qbase + quad * 4 + r;
#pragma unroll
    for (int nt2 = 0; nt2 < 4; ++nt2)
      ybuf[row * Dd + h * 64 + nt2 * 16 + l16] = f2bf(acc[nt2][r] * li);
  }
}

// ---------------------------------------------------------------- launcher
extern "C" void kernel_launch(void* const* d_in, const int* in_sizes, int n_in,
                              void* d_out, int out_size, void* d_ws, size_t ws_size,
                              hipStream_t stream) {
  (void)in_sizes; (void)n_in; (void)out_size; (void)ws_size;
  const float* x = (const float*)d_in[0];
  const int* mask = (const int*)d_in[1];
  const float* gamma = (const float*)d_in[2];
  const float* beta = (const float*)d_in[3];
  const float* Wq = (const float*)d_in[4];
  const float* bq = (const float*)d_in[5];
  const float* Wk = (const float*)d_in[6];
  const float* bk = (const float*)d_in[7];
  const float* Wv = (const float*)d_in[8];
  const float* bv = (const float*)d_in[9];
  const float* Wo = (const float*)d_in[10];
  const float* bo = (const float*)d_in[11];
  float* out = (float*)d_out;
  char* ws = (char*)d_ws;

  constexpr size_t SZ_XN = (size_t)4096 * 1024 * 2;
  constexpr size_t SZ_WTQ = (size_t)3072 * 1024 * 2;
  constexpr size_t SZ_WOT = (size_t)1024 * 1024 * 2;
  constexpr size_t SZ_B3 = 3072 * 4;
  constexpr size_t SZ_QKV = (size_t)4096 * 2048 * 2;   // Q|K only (ld 2048)
  constexpr size_t SZ_MBITS = (size_t)2 * 64 * 2048 * 4;
  constexpr size_t SZ_VT = (size_t)1024 * 4096 * 2;    // V^T (ld 4096)
  size_t off = 0;
  u16* xn = (u16*)(ws + off); off += SZ_XN;
  u16* wtqkv = (u16*)(ws + off); off += SZ_WTQ;
  u16* wot = (u16*)(ws + off); off += SZ_WOT;
  float* bias3 = (float*)(ws + off); off += SZ_B3;
  u16* qkvb = (u16*)(ws + off); off += SZ_QKV;
  uint32_t* mbits = (uint32_t*)(ws + off); off += SZ_MBITS;
  u16* vtb = (u16*)(ws + off); off += SZ_VT;
  u16* ybuf = (u16*)(ws + off);

  prep_kernel<<<dim3(9228), dim3(256), 0, stream>>>(
      x, gamma, beta, xn, Wq, Wk, Wv, Wo, wtqkv, wot, mask, mbits, bq, bk, bv,
      bias3);
  qkvt_gemm<<<dim3(768), dim3(256), 0, stream>>>(xn, wtqkv, bias3, qkvb, vtb);
  attn_kernel<<<dim3(16, 16, 2), dim3(512), 0, stream>>>(qkvb, vtb, mbits, ybuf);
  gemm_bt<64><<<dim3(8, 64), dim3(256), 0, stream>>>(
      ybuf, wot, bo, x, out, 1024, 1024);
}